// Round 4
// baseline (532.934 us; speedup 1.0000x reference)
//
#include <hip/hip_runtime.h>
#include <hip/hip_bf16.h>

#define NTOT 8192
#define DDIM 256
#define ROWS 32                 // rows per block
#define JB 32                   // j per inner iteration (one MFMA K)
#define JCHUNK (NTOT / 8)       // 1024 j per wave (8 waves, j-split)
#define NITER (JCHUNK / JB)     // 32

typedef __attribute__((ext_vector_type(8))) short short8;
typedef __attribute__((ext_vector_type(4))) float floatx4;

// ---------------- per-row scores s1 = h@a[:D], s2 = h@a[D:] -----------------
__global__ __launch_bounds__(256) void gat_scores(const float* __restrict__ h,
                                                  const float* __restrict__ a,
                                                  float* __restrict__ s1,
                                                  float* __restrict__ s2) {
  int row  = blockIdx.x * 4 + (threadIdx.x >> 6);
  int lane = threadIdx.x & 63;
  const float* hr = h + (size_t)row * DDIM;
  float p1 = 0.f, p2 = 0.f;
#pragma unroll
  for (int k = 0; k < DDIM / 64; ++k) {
    int idx  = lane + 64 * k;
    float hv = hr[idx];
    p1 += hv * a[idx];
    p2 += hv * a[DDIM + idx];
  }
#pragma unroll
  for (int off = 32; off > 0; off >>= 1) {
    p1 += __shfl_down(p1, off, 64);
    p2 += __shfl_down(p2, off, 64);
  }
  if (lane == 0) { s1[row] = p1; s2[row] = p2; }
}

// ---------------- hT[d][i] = bf16(h[i][d]) ----------------------------------
__global__ __launch_bounds__(256) void gat_transpose(const float* __restrict__ h,
                                                     ushort* __restrict__ hT) {
  __shared__ float tile[64][65];
  const int i0 = blockIdx.x * 64, d0 = blockIdx.y * 64;
  const int t = threadIdx.x;
  const int c = t & 63, r4 = t >> 6;
#pragma unroll
  for (int it = 0; it < 16; ++it) {
    int r = r4 + 4 * it;
    tile[r][c] = h[(size_t)(i0 + r) * DDIM + d0 + c];
  }
  __syncthreads();
#pragma unroll
  for (int it = 0; it < 16; ++it) {
    int d = r4 + 4 * it;
    float v = tile[c][d];
    __hip_bfloat16 b = __float2bfloat16(v);
    hT[(size_t)(d0 + d) * NTOT + i0 + c] = *(ushort*)&b;
  }
}

// ---------------- barrier-free fused softmax + P@h via MFMA -----------------
// 256 blocks x 512 thr. Block owns rows [r0, r0+32); wave w owns j-chunk
// [1024w, 1024w+1024). P-fragments built in registers in MFMA A-layout
// (lane -> A[m=lane&15][k=quad*8+jj]); acc = full 32x256 per wave (128 VGPR).
// No LDS / no barriers in the K-loop; single LDS tree-reduce at the end.
__global__ __launch_bounds__(512, 2) void gat_attn(const ushort* __restrict__ hT,
                                                   const int*   __restrict__ adj,
                                                   const float* __restrict__ s1g,
                                                   const float* __restrict__ s2g,
                                                   float* __restrict__ out) {
  __shared__ union {
    float lred[8][32];            // per-wave row-sum partials (early phase)
    float slab[4][ROWS * 128];    // 64 KB reduction slab (late phase)
  } sh;

  const int t    = threadIdx.x;
  const int lane = t & 63;
  const int w    = t >> 6;
  const int quad = lane >> 4;
  const int c    = lane & 15;
  const int r0   = blockIdx.x * ROWS;

  const float s10 = s1g[r0 + c];        // A-row for frag rt=0
  const float s11 = s1g[r0 + 16 + c];   // A-row for frag rt=1

  const int*   ap0 = adj + (size_t)(r0 + c) * NTOT + w * JCHUNK + 8 * quad;
  const int*   ap1 = adj + (size_t)(r0 + 16 + c) * NTOT + w * JCHUNK + 8 * quad;
  const float* s2p = s2g + w * JCHUNK + 8 * quad;
  const ushort* hb = hT + (size_t)c * NTOT + w * JCHUNK + 8 * quad;

  floatx4 acc[2][16];
#pragma unroll
  for (int rt = 0; rt < 2; ++rt)
#pragma unroll
    for (int nt = 0; nt < 16; ++nt) acc[rt][nt] = (floatx4){0.f, 0.f, 0.f, 0.f};

  float lp0 = 0.f, lp1 = 0.f;

  // depth-2 register prefetch rings (adj + s2), two parity buffers
  int4   a0[2][2], a1[2][2];
  float4 s2r[2][2];
#pragma unroll
  for (int pb = 0; pb < 2; ++pb) {
    a0[pb][0]  = ((const int4*)(ap0 + pb * JB))[0];
    a0[pb][1]  = ((const int4*)(ap0 + pb * JB))[1];
    a1[pb][0]  = ((const int4*)(ap1 + pb * JB))[0];
    a1[pb][1]  = ((const int4*)(ap1 + pb * JB))[1];
    s2r[pb][0] = ((const float4*)(s2p + pb * JB))[0];
    s2r[pb][1] = ((const float4*)(s2p + pb * JB))[1];
  }

  auto body = [&](int jt, int4* A0, int4* A1, float4* S2) {
    // ---- build P A-frags in registers: p = adj ? exp(lrelu(s1+s2)) : 0 ----
    short8 pa0, pa1;
    const int*   m0 = (const int*)A0;
    const int*   m1 = (const int*)A1;
    const float* sv = (const float*)S2;
#pragma unroll
    for (int i = 0; i < 8; ++i) {
      float e0 = s10 + sv[i];
      e0 = e0 > 0.f ? e0 : 0.01f * e0;
      float p0 = m0[i] > 0 ? __expf(e0) : 0.f;
      lp0 += p0;
      __hip_bfloat16 b0 = __float2bfloat16(p0);
      pa0[i] = *(short*)&b0;
      float e1 = s11 + sv[i];
      e1 = e1 > 0.f ? e1 : 0.01f * e1;
      float p1 = m1[i] > 0 ? __expf(e1) : 0.f;
      lp1 += p1;
      __hip_bfloat16 b1 = __float2bfloat16(p1);
      pa1[i] = *(short*)&b1;
    }
    // ---- prefetch jt+2 into the same parity buffers ----
    if (jt + 2 < NITER) {
      const int off = (jt + 2) * JB;
      A0[0] = ((const int4*)(ap0 + off))[0];
      A0[1] = ((const int4*)(ap0 + off))[1];
      A1[0] = ((const int4*)(ap1 + off))[0];
      A1[1] = ((const int4*)(ap1 + off))[1];
      S2[0] = ((const float4*)(s2p + off))[0];
      S2[1] = ((const float4*)(s2p + off))[1];
    }
    // ---- 32 MFMA: B-frags from L2-resident hT, reused across both row-frags
    const ushort* hbt = hb + jt * JB;
#pragma unroll
    for (int nt = 0; nt < 16; ++nt) {
      short8 bfr = *(const short8*)(hbt + (size_t)(nt * 16) * NTOT);
      acc[0][nt] = __builtin_amdgcn_mfma_f32_16x16x32_bf16(pa0, bfr, acc[0][nt], 0, 0, 0);
      acc[1][nt] = __builtin_amdgcn_mfma_f32_16x16x32_bf16(pa1, bfr, acc[1][nt], 0, 0, 0);
    }
  };

  for (int jt2 = 0; jt2 < NITER; jt2 += 2) {
    body(jt2,     a0[0], a1[0], s2r[0]);
    body(jt2 + 1, a0[1], a1[1], s2r[1]);
  }

  // ---- row-sum reduce: quads -> lanes 0-15, then LDS across waves ----
  lp0 += __shfl_xor(lp0, 16, 64); lp0 += __shfl_xor(lp0, 32, 64);
  lp1 += __shfl_xor(lp1, 16, 64); lp1 += __shfl_xor(lp1, 32, 64);
  if (quad == 0) { sh.lred[w][c] = lp0; sh.lred[w][16 + c] = lp1; }
  __syncthreads();

  float linv[2][4];                       // wave 0 only: 1/l for its C-rows
  if (w == 0) {
#pragma unroll
    for (int rt = 0; rt < 2; ++rt)
#pragma unroll
      for (int reg = 0; reg < 4; ++reg) {
        int lrow = rt * 16 + quad * 4 + reg;
        float s = 0.f;
#pragma unroll
        for (int wi = 0; wi < 8; ++wi) s += sh.lred[wi][lrow];
        linv[rt][reg] = 1.f / s;
      }
  }
  __syncthreads();                        // lred no longer needed; slab reuse ok

  // ---- log-depth acc reduction over 8 waves, per 128-col half ----
#pragma unroll
  for (int hd = 0; hd < 2; ++hd) {
    // round 1: waves 4-7 -> slab, waves 0-3 add
    if (w >= 4) {
#pragma unroll
      for (int rt = 0; rt < 2; ++rt)
#pragma unroll
        for (int i = 0; i < 8; ++i)
#pragma unroll
          for (int reg = 0; reg < 4; ++reg)
            sh.slab[w - 4][(rt * 16 + quad * 4 + reg) * 128 + i * 16 + c] =
                acc[rt][i + 8 * hd][reg];
    }
    __syncthreads();
    if (w < 4) {
#pragma unroll
      for (int rt = 0; rt < 2; ++rt)
#pragma unroll
        for (int i = 0; i < 8; ++i)
#pragma unroll
          for (int reg = 0; reg < 4; ++reg)
            acc[rt][i + 8 * hd][reg] +=
                sh.slab[w][(rt * 16 + quad * 4 + reg) * 128 + i * 16 + c];
    }
    __syncthreads();
    // round 2: waves 2-3 -> slab, waves 0-1 add
    if (w == 2 || w == 3) {
#pragma unroll
      for (int rt = 0; rt < 2; ++rt)
#pragma unroll
        for (int i = 0; i < 8; ++i)
#pragma unroll
          for (int reg = 0; reg < 4; ++reg)
            sh.slab[w - 2][(rt * 16 + quad * 4 + reg) * 128 + i * 16 + c] =
                acc[rt][i + 8 * hd][reg];
    }
    __syncthreads();
    if (w < 2) {
#pragma unroll
      for (int rt = 0; rt < 2; ++rt)
#pragma unroll
        for (int i = 0; i < 8; ++i)
#pragma unroll
          for (int reg = 0; reg < 4; ++reg)
            acc[rt][i + 8 * hd][reg] +=
                sh.slab[w][(rt * 16 + quad * 4 + reg) * 128 + i * 16 + c];
    }
    __syncthreads();
    // round 3: wave 1 -> slab, wave 0 adds + normalizes + stores
    if (w == 1) {
#pragma unroll
      for (int rt = 0; rt < 2; ++rt)
#pragma unroll
        for (int i = 0; i < 8; ++i)
#pragma unroll
          for (int reg = 0; reg < 4; ++reg)
            sh.slab[0][(rt * 16 + quad * 4 + reg) * 128 + i * 16 + c] =
                acc[rt][i + 8 * hd][reg];
    }
    __syncthreads();
    if (w == 0) {
#pragma unroll
      for (int rt = 0; rt < 2; ++rt)
#pragma unroll
        for (int i = 0; i < 8; ++i)
#pragma unroll
          for (int reg = 0; reg < 4; ++reg) {
            float v = acc[rt][i + 8 * hd][reg] +
                      sh.slab[0][(rt * 16 + quad * 4 + reg) * 128 + i * 16 + c];
            out[(size_t)(r0 + rt * 16 + quad * 4 + reg) * DDIM +
                hd * 128 + i * 16 + c] = v * linv[rt][reg];
          }
    }
    __syncthreads();                     // protect slab before next half
  }
}

extern "C" void kernel_launch(void* const* d_in, const int* in_sizes, int n_in,
                              void* d_out, int out_size, void* d_ws, size_t ws_size,
                              hipStream_t stream) {
  const float* h   = (const float*)d_in[0];
  const int*   adj = (const int*)d_in[1];
  const float* a   = (const float*)d_in[2];
  float* out = (float*)d_out;

  float*  s1 = (float*)d_ws;                 // NTOT floats
  float*  s2 = s1 + NTOT;                    // NTOT floats
  ushort* hT = (ushort*)(s2 + NTOT);         // DDIM*NTOT bf16 = 4 MB

  gat_scores<<<NTOT / 4, 256, 0, stream>>>(h, a, s1, s2);
  gat_transpose<<<dim3(NTOT / 64, DDIM / 64), 256, 0, stream>>>(h, hT);
  gat_attn<<<NTOT / ROWS, 512, 0, stream>>>(hT, adj, s1, s2, out);
}

// Round 5
// 454.235 us; speedup vs baseline: 1.1733x; 1.1733x over previous
//
#include <hip/hip_runtime.h>
#include <hip/hip_bf16.h>

#define NTOT 8192
#define DDIM 256
#define ROWS 32                 // rows per attn block
#define JCHUNK (NTOT / 8)       // 1024 j per wave (8 waves j-split in block)
#define NITER (JCHUNK / 32)     // 32 K-tiles per wave
#define NWORDS (NTOT / 32)      // 256 bitmask words per row

typedef __attribute__((ext_vector_type(8))) short short8;
typedef __attribute__((ext_vector_type(4))) float floatx4;

// ---------------- per-row scores s1 = h@a[:D], s2 = h@a[D:] -----------------
__global__ __launch_bounds__(256) void gat_scores(const float* __restrict__ h,
                                                  const float* __restrict__ a,
                                                  float* __restrict__ s1,
                                                  float* __restrict__ s2) {
  int row  = blockIdx.x * 4 + (threadIdx.x >> 6);
  int lane = threadIdx.x & 63;
  const float* hr = h + (size_t)row * DDIM;
  float p1 = 0.f, p2 = 0.f;
#pragma unroll
  for (int k = 0; k < DDIM / 64; ++k) {
    int idx  = lane + 64 * k;
    float hv = hr[idx];
    p1 += hv * a[idx];
    p2 += hv * a[DDIM + idx];
  }
#pragma unroll
  for (int off = 32; off > 0; off >>= 1) {
    p1 += __shfl_down(p1, off, 64);
    p2 += __shfl_down(p2, off, 64);
  }
  if (lane == 0) { s1[row] = p1; s2[row] = p2; }
}

// ---------------- pack adj -> word-major bitmask bitsT[jw][row] -------------
// Block: 64 rows x 2048 j. Coalesced int4 reads; shfl-assembled 32-bit words;
// LDS transpose so the global write is row-contiguous per word-index.
__global__ __launch_bounds__(256) void gat_pack(const int* __restrict__ adj,
                                                unsigned* __restrict__ bitsT) {
  __shared__ unsigned words[64][65];   // [row_local][jw_local], +1 pad
  const int t    = threadIdx.x;
  const int lane = t & 63;
  const int w    = t >> 6;
  const int r0   = blockIdx.x * 64;
  const int jb   = blockIdx.y * 2048;

  // phase A: each wave covers 16 rows x 2048 j (8 rounds of 256 j)
#pragma unroll 2
  for (int rr = 0; rr < 16; ++rr) {
    const int rl = w * 16 + rr;
    const int* ap = adj + (size_t)(r0 + rl) * NTOT + jb + lane * 4;
#pragma unroll
    for (int R = 0; R < 8; ++R) {
      int4 v = *(const int4*)(ap + R * 256);          // 1KB contiguous per wave
      unsigned nib = (v.x > 0 ? 1u : 0u) | (v.y > 0 ? 2u : 0u) |
                     (v.z > 0 ? 4u : 0u) | (v.w > 0 ? 8u : 0u);
      unsigned b8  = nib | (__shfl_xor((int)nib, 1, 64) << 4);
      unsigned b16 = b8  | (__shfl_xor((int)b8,  2, 64) << 8);
      unsigned b32 = b16 | (__shfl_xor((int)b16, 4, 64) << 16);
      if ((lane & 7) == 0) words[rl][R * 8 + (lane >> 3)] = b32;
    }
  }
  __syncthreads();

  // phase B: write bitsT[jw][row] -- 256B contiguous per wave-store
#pragma unroll 4
  for (int kk = 0; kk < 16; ++kk) {
    const int jwl = w * 16 + kk;
    bitsT[(size_t)(jb / 32 + jwl) * NTOT + r0 + lane] = words[lane][jwl];
  }
}

// ---------------- pack h -> fragment-major bf16 hTf -------------------------
// hTf element ((n*256 + jblk)*64 + lane)*8 + i = H[jblk*32 + (lane>>4)*8 + i][n*16 + (lane&15)]
__global__ __launch_bounds__(256) void gat_hpack(const float* __restrict__ h,
                                                 ushort* __restrict__ hTf) {
  __shared__ float tile[64][257];
  const int t    = threadIdx.x;
  const int lane = t & 63;
  const int w    = t >> 6;
  const int quad = lane >> 4;
  const int c    = lane & 15;
  const int i0   = blockIdx.x * 64;

#pragma unroll
  for (int it = 0; it < 16; ++it) {
    int r = it * 4 + w;
    float4 v = *(const float4*)(h + (size_t)(i0 + r) * DDIM + lane * 4);
    tile[r][lane * 4 + 0] = v.x; tile[r][lane * 4 + 1] = v.y;
    tile[r][lane * 4 + 2] = v.z; tile[r][lane * 4 + 3] = v.w;
  }
  __syncthreads();

#pragma unroll
  for (int k = 0; k < 4; ++k) {
    const int n = 4 * k + w;
#pragma unroll
    for (int jbl = 0; jbl < 2; ++jbl) {
      short8 vv;
#pragma unroll
      for (int i = 0; i < 8; ++i) {
        float f = tile[jbl * 32 + quad * 8 + i][n * 16 + c];
        __hip_bfloat16 b = __float2bfloat16(f);
        vv[i] = *(short*)&b;
      }
      *(short8*)(hTf + ((size_t)(n * 256 + i0 / 32 + jbl) * 64 + lane) * 8) = vv;
    }
  }
}

// ---------------- barrier-free fused softmax + P@h via MFMA -----------------
// 256 blocks x 512 thr. Block rows [r0,r0+32); wave w: j in [1024w,1024w+1024).
// All hot loads contiguous: B-frags 1KB bursts from hTf, masks 64B from bitsT.
__global__ __launch_bounds__(512, 2) void gat_attn(const ushort* __restrict__ hTf,
                                                   const unsigned* __restrict__ bitsT,
                                                   const float* __restrict__ s1g,
                                                   const float* __restrict__ s2g,
                                                   float* __restrict__ out) {
  __shared__ union {
    float lred[8][32];
    float slab[4][ROWS * 128];
  } sh;

  const int t    = threadIdx.x;
  const int lane = t & 63;
  const int w    = t >> 6;
  const int quad = lane >> 4;
  const int c    = lane & 15;
  const int r0   = blockIdx.x * ROWS;

  const float s10 = s1g[r0 + c];
  const float s11 = s1g[r0 + 16 + c];

  const unsigned* btp = bitsT + (size_t)(w * 32) * NTOT;
  const float*    s2p = s2g + w * JCHUNK + 8 * quad;
  const ushort*   hfp = hTf + (size_t)(w * 32) * 512 + lane * 8;

  floatx4 acc[2][16];
#pragma unroll
  for (int rt = 0; rt < 2; ++rt)
#pragma unroll
    for (int nt = 0; nt < 16; ++nt) acc[rt][nt] = (floatx4){0.f, 0.f, 0.f, 0.f};

  float lp0 = 0.f, lp1 = 0.f;

  // depth-1 prefetch of mask words + s2
  unsigned W0 = btp[r0 + c];
  unsigned W1 = btp[r0 + 16 + c];
  float4 sa = ((const float4*)s2p)[0];
  float4 sb = ((const float4*)s2p)[1];

  for (int jt = 0; jt < NITER; ++jt) {
    // ---- issue all 16 B-frag loads first (each 1KB contiguous/wave) ----
    short8 bfr[16];
    const ushort* hp = hfp + (size_t)jt * 512;
#pragma unroll
    for (int nt = 0; nt < 16; ++nt)
      bfr[nt] = *(const short8*)(hp + (size_t)nt * 131072);

    // ---- build P A-frags in registers (hides B-load latency) ----
    const unsigned bm0 = (W0 >> (quad * 8)) & 0xff;
    const unsigned bm1 = (W1 >> (quad * 8)) & 0xff;
    float sv[8] = {sa.x, sa.y, sa.z, sa.w, sb.x, sb.y, sb.z, sb.w};
    short8 pa0, pa1;
#pragma unroll
    for (int i = 0; i < 8; ++i) {
      float e0 = s10 + sv[i];
      e0 = fmaxf(e0, 0.01f * e0);              // leaky_relu(0.01)
      float p0 = ((bm0 >> i) & 1) ? __expf(e0) : 0.f;
      lp0 += p0;
      __hip_bfloat16 b0 = __float2bfloat16(p0);
      pa0[i] = *(short*)&b0;
      float e1 = s11 + sv[i];
      e1 = fmaxf(e1, 0.01f * e1);
      float p1 = ((bm1 >> i) & 1) ? __expf(e1) : 0.f;
      lp1 += p1;
      __hip_bfloat16 b1 = __float2bfloat16(p1);
      pa1[i] = *(short*)&b1;
    }

    // ---- prefetch next tile's mask words + s2 ----
    if (jt + 1 < NITER) {
      W0 = btp[(size_t)(jt + 1) * NTOT + r0 + c];
      W1 = btp[(size_t)(jt + 1) * NTOT + r0 + 16 + c];
      sa = ((const float4*)(s2p + (jt + 1) * 32))[0];
      sb = ((const float4*)(s2p + (jt + 1) * 32))[1];
    }

    // ---- 32 MFMAs, B-frags reused across both row-fragments ----
#pragma unroll
    for (int nt = 0; nt < 16; ++nt) {
      acc[0][nt] = __builtin_amdgcn_mfma_f32_16x16x32_bf16(pa0, bfr[nt], acc[0][nt], 0, 0, 0);
      acc[1][nt] = __builtin_amdgcn_mfma_f32_16x16x32_bf16(pa1, bfr[nt], acc[1][nt], 0, 0, 0);
    }
  }

  // ---- row-sum reduce: quads -> lanes 0-15, then LDS across waves ----
  lp0 += __shfl_xor(lp0, 16, 64); lp0 += __shfl_xor(lp0, 32, 64);
  lp1 += __shfl_xor(lp1, 16, 64); lp1 += __shfl_xor(lp1, 32, 64);
  if (quad == 0) { sh.lred[w][c] = lp0; sh.lred[w][16 + c] = lp1; }
  __syncthreads();

  float linv[2][4];
  if (w == 0) {
#pragma unroll
    for (int rt = 0; rt < 2; ++rt)
#pragma unroll
      for (int reg = 0; reg < 4; ++reg) {
        int lrow = rt * 16 + quad * 4 + reg;
        float s = 0.f;
#pragma unroll
        for (int wi = 0; wi < 8; ++wi) s += sh.lred[wi][lrow];
        linv[rt][reg] = 1.f / s;
      }
  }
  __syncthreads();

  // ---- log-depth acc reduction over 8 waves, per 128-col half ----
#pragma unroll
  for (int hd = 0; hd < 2; ++hd) {
    if (w >= 4) {
#pragma unroll
      for (int rt = 0; rt < 2; ++rt)
#pragma unroll
        for (int i = 0; i < 8; ++i)
#pragma unroll
          for (int reg = 0; reg < 4; ++reg)
            sh.slab[w - 4][(rt * 16 + quad * 4 + reg) * 128 + i * 16 + c] =
                acc[rt][i + 8 * hd][reg];
    }
    __syncthreads();
    if (w < 4) {
#pragma unroll
      for (int rt = 0; rt < 2; ++rt)
#pragma unroll
        for (int i = 0; i < 8; ++i)
#pragma unroll
          for (int reg = 0; reg < 4; ++reg)
            acc[rt][i + 8 * hd][reg] +=
                sh.slab[w][(rt * 16 + quad * 4 + reg) * 128 + i * 16 + c];
    }
    __syncthreads();
    if (w == 2 || w == 3) {
#pragma unroll
      for (int rt = 0; rt < 2; ++rt)
#pragma unroll
        for (int i = 0; i < 8; ++i)
#pragma unroll
          for (int reg = 0; reg < 4; ++reg)
            sh.slab[w - 2][(rt * 16 + quad * 4 + reg) * 128 + i * 16 + c] =
                acc[rt][i + 8 * hd][reg];
    }
    __syncthreads();
    if (w < 2) {
#pragma unroll
      for (int rt = 0; rt < 2; ++rt)
#pragma unroll
        for (int i = 0; i < 8; ++i)
#pragma unroll
          for (int reg = 0; reg < 4; ++reg)
            acc[rt][i + 8 * hd][reg] +=
                sh.slab[w][(rt * 16 + quad * 4 + reg) * 128 + i * 16 + c];
    }
    __syncthreads();
    if (w == 1) {
#pragma unroll
      for (int rt = 0; rt < 2; ++rt)
#pragma unroll
        for (int i = 0; i < 8; ++i)
#pragma unroll
          for (int reg = 0; reg < 4; ++reg)
            sh.slab[0][(rt * 16 + quad * 4 + reg) * 128 + i * 16 + c] =
                acc[rt][i + 8 * hd][reg];
    }
    __syncthreads();
    if (w == 0) {
#pragma unroll
      for (int rt = 0; rt < 2; ++rt)
#pragma unroll
        for (int i = 0; i < 8; ++i)
#pragma unroll
          for (int reg = 0; reg < 4; ++reg) {
            float v = acc[rt][i + 8 * hd][reg] +
                      sh.slab[0][(rt * 16 + quad * 4 + reg) * 128 + i * 16 + c];
            out[(size_t)(r0 + rt * 16 + quad * 4 + reg) * DDIM +
                hd * 128 + i * 16 + c] = v * linv[rt][reg];
          }
    }
    __syncthreads();
  }
}

extern "C" void kernel_launch(void* const* d_in, const int* in_sizes, int n_in,
                              void* d_out, int out_size, void* d_ws, size_t ws_size,
                              hipStream_t stream) {
  const float* h   = (const float*)d_in[0];
  const int*   adj = (const int*)d_in[1];
  const float* a   = (const float*)d_in[2];
  float* out = (float*)d_out;

  float*    s1    = (float*)d_ws;                       // 8192 f32
  float*    s2    = s1 + NTOT;                          // 8192 f32
  unsigned* bitsT = (unsigned*)(s2 + NTOT);             // 256*8192 u32 = 8 MB
  ushort*   hTf   = (ushort*)(bitsT + (size_t)NWORDS * NTOT);  // 4 MB bf16

  gat_scores<<<NTOT / 4, 256, 0, stream>>>(h, a, s1, s2);
  gat_pack<<<dim3(NTOT / 64, 4), 256, 0, stream>>>(adj, bitsT);
  gat_hpack<<<NTOT / 64, 256, 0, stream>>>(h, hTf);
  gat_attn<<<NTOT / ROWS, 512, 0, stream>>>(hTf, bitsT, s1, s2, out);
}

// Round 6
// 453.952 us; speedup vs baseline: 1.1740x; 1.0006x over previous
//
#include <hip/hip_runtime.h>
#include <hip/hip_bf16.h>

#define NTOT 8192
#define DDIM 256
#define ROWS 32                 // rows per attn block
#define JCHUNK (NTOT / 8)       // 1024 j per wave (8 waves j-split in block)
#define NITER (JCHUNK / 32)     // 32 K-tiles per wave
#define NWORDS (NTOT / 32)      // 256 bitmask words per row
#define NTSTR 131584            // hTf nt-stride in elems: 257*64*8 (+1KB/256KB, breaks L2 channel aliasing)

typedef __attribute__((ext_vector_type(8))) short short8;
typedef __attribute__((ext_vector_type(4))) float floatx4;

// ------- per-row scores + exp tables: s1,s2, rc=(e^s1,e^.01s1,e^-s1), etab=(e^s2,e^.01s2)
__global__ __launch_bounds__(256) void gat_scores(const float* __restrict__ h,
                                                  const float* __restrict__ a,
                                                  float* __restrict__ s1,
                                                  float* __restrict__ s2,
                                                  float4* __restrict__ rc,
                                                  float2* __restrict__ etab) {
  int row  = blockIdx.x * 4 + (threadIdx.x >> 6);
  int lane = threadIdx.x & 63;
  const float* hr = h + (size_t)row * DDIM;
  float p1 = 0.f, p2 = 0.f;
#pragma unroll
  for (int k = 0; k < DDIM / 64; ++k) {
    int idx  = lane + 64 * k;
    float hv = hr[idx];
    p1 += hv * a[idx];
    p2 += hv * a[DDIM + idx];
  }
#pragma unroll
  for (int off = 32; off > 0; off >>= 1) {
    p1 += __shfl_down(p1, off, 64);
    p2 += __shfl_down(p2, off, 64);
  }
  if (lane == 0) {
    s1[row] = p1; s2[row] = p2;
    rc[row]   = make_float4(__expf(p1), __expf(0.01f * p1), __expf(-p1), 0.f);
    etab[row] = make_float2(__expf(p2), __expf(0.01f * p2));
  }
}

// ---------------- pack adj -> word-major bitmask bitsT[jw][row] -------------
__global__ __launch_bounds__(256) void gat_pack(const int* __restrict__ adj,
                                                unsigned* __restrict__ bitsT) {
  __shared__ unsigned words[64][65];
  const int t    = threadIdx.x;
  const int lane = t & 63;
  const int w    = t >> 6;
  const int r0   = blockIdx.x * 64;
  const int jb   = blockIdx.y * 2048;

#pragma unroll 2
  for (int rr = 0; rr < 16; ++rr) {
    const int rl = w * 16 + rr;
    const int* ap = adj + (size_t)(r0 + rl) * NTOT + jb + lane * 4;
#pragma unroll
    for (int R = 0; R < 8; ++R) {
      int4 v = *(const int4*)(ap + R * 256);
      unsigned nib = (v.x > 0 ? 1u : 0u) | (v.y > 0 ? 2u : 0u) |
                     (v.z > 0 ? 4u : 0u) | (v.w > 0 ? 8u : 0u);
      unsigned b8  = nib | (__shfl_xor((int)nib, 1, 64) << 4);
      unsigned b16 = b8  | (__shfl_xor((int)b8,  2, 64) << 8);
      unsigned b32 = b16 | (__shfl_xor((int)b16, 4, 64) << 16);
      if ((lane & 7) == 0) words[rl][R * 8 + (lane >> 3)] = b32;
    }
  }
  __syncthreads();

#pragma unroll 4
  for (int kk = 0; kk < 16; ++kk) {
    const int jwl = w * 16 + kk;
    bitsT[(size_t)(jb / 32 + jwl) * NTOT + r0 + lane] = words[lane][jwl];
  }
}

// ---------------- pack h -> fragment-major bf16 hTf (padded nt-stride) ------
// hTf[((n*257 + jblk)*64 + lane)*8 + i] = H[jblk*32 + (lane>>4)*8 + i][n*16 + (lane&15)]
__global__ __launch_bounds__(256) void gat_hpack(const float* __restrict__ h,
                                                 ushort* __restrict__ hTf) {
  __shared__ float tile[64][257];
  const int t    = threadIdx.x;
  const int lane = t & 63;
  const int w    = t >> 6;
  const int quad = lane >> 4;
  const int c    = lane & 15;
  const int i0   = blockIdx.x * 64;

#pragma unroll
  for (int it = 0; it < 16; ++it) {
    int r = it * 4 + w;
    float4 v = *(const float4*)(h + (size_t)(i0 + r) * DDIM + lane * 4);
    tile[r][lane * 4 + 0] = v.x; tile[r][lane * 4 + 1] = v.y;
    tile[r][lane * 4 + 2] = v.z; tile[r][lane * 4 + 3] = v.w;
  }
  __syncthreads();

#pragma unroll
  for (int k = 0; k < 4; ++k) {
    const int n = 4 * k + w;
#pragma unroll
    for (int jbl = 0; jbl < 2; ++jbl) {
      short8 vv;
#pragma unroll
      for (int i = 0; i < 8; ++i) {
        float f = tile[jbl * 32 + quad * 8 + i][n * 16 + c];
        __hip_bfloat16 b = __float2bfloat16(f);
        vv[i] = *(short*)&b;
      }
      *(short8*)(hTf + ((size_t)(n * 257 + i0 / 32 + jbl) * 64 + lane) * 8) = vv;
    }
  }
}

// ---------------- barrier-free fused softmax + P@h via MFMA -----------------
// 256 blocks x 512 thr. Block rows [r0,r0+32); wave w: j in [1024w,1024w+1024).
// No v_exp in loop (factored tables); B-frags pipelined in 2 groups of 8.
__global__ __launch_bounds__(512, 2) void gat_attn(const ushort* __restrict__ hTf,
                                                   const unsigned* __restrict__ bitsT,
                                                   const float4* __restrict__ rc,
                                                   const float2* __restrict__ etab,
                                                   float* __restrict__ out) {
  __shared__ union {
    float lred[8][32];
    float slab[4][ROWS * 128];
  } sh;

  const int t    = threadIdx.x;
  const int lane = t & 63;
  const int w    = t >> 6;
  const int quad = lane >> 4;
  const int c    = lane & 15;
  const int r0   = blockIdx.x * ROWS;

  const float4 rc0 = rc[r0 + c];        // (E1, E2, T) for A-row frag 0
  const float4 rc1 = rc[r0 + 16 + c];   // for A-row frag 1
  const float E10 = rc0.x, E20 = rc0.y, T0 = rc0.z;
  const float E11 = rc1.x, E21 = rc1.y, T1 = rc1.z;

  const unsigned* btp = bitsT + (size_t)(w * 32) * NTOT;
  const float*    etb = (const float*)(etab + (size_t)w * JCHUNK + quad * 8);
  const ushort*   hfp = hTf + ((size_t)(w * 32) * 64 + lane) * 8;

  floatx4 acc[2][16];
#pragma unroll
  for (int rt = 0; rt < 2; ++rt)
#pragma unroll
    for (int nt = 0; nt < 16; ++nt) acc[rt][nt] = (floatx4){0.f, 0.f, 0.f, 0.f};

  float lp0 = 0.f, lp1 = 0.f;
  short8 bA[8], bB[8];

  // prologue: first half-0 B-frags + first mask/etab
  #define LDH(dst, jt, half)                                                   \
    _Pragma("unroll")                                                          \
    for (int q = 0; q < 8; ++q)                                                \
      dst[q] = *(const short8*)(hfp + (size_t)(jt) * 512 +                     \
                                (size_t)((half) * 8 + q) * NTSTR);

  LDH(bA, 0, 0)
  unsigned W0 = btp[r0 + c];
  unsigned W1 = btp[r0 + 16 + c];
  float4 ea = ((const float4*)etb)[0];
  float4 eb = ((const float4*)etb)[1];
  float4 ec = ((const float4*)etb)[2];
  float4 ed = ((const float4*)etb)[3];

  for (int jt = 0; jt < NITER; ++jt) {
    // ---- issue half-1 B-frag loads (land during P-build) ----
    LDH(bB, jt, 1)

    // ---- P-build from tables: p = bit * (t1>T ? E1*t1 : E2*t2) ----
    const unsigned bm0 = (W0 >> (quad * 8)) & 0xff;
    const unsigned bm1 = (W1 >> (quad * 8)) & 0xff;
    float tp[16] = {ea.x, ea.y, ea.z, ea.w, eb.x, eb.y, eb.z, eb.w,
                    ec.x, ec.y, ec.z, ec.w, ed.x, ed.y, ed.z, ed.w};
    short8 pa0, pa1;
#pragma unroll
    for (int i = 0; i < 8; ++i) {
      const float t1 = tp[2 * i], t2 = tp[2 * i + 1];
      const float m0 = (float)((bm0 >> i) & 1u);
      const float m1 = (float)((bm1 >> i) & 1u);
      float p0 = ((t1 > T0) ? E10 * t1 : E20 * t2) * m0;
      float p1 = ((t1 > T1) ? E11 * t1 : E21 * t2) * m1;
      lp0 += p0; lp1 += p1;
      __hip_bfloat16 b0 = __float2bfloat16(p0);
      __hip_bfloat16 b1 = __float2bfloat16(p1);
      pa0[i] = *(short*)&b0;
      pa1[i] = *(short*)&b1;
    }

    // ---- prefetch next body's mask words + etab ----
    if (jt + 1 < NITER) {
      W0 = btp[(size_t)(jt + 1) * NTOT + r0 + c];
      W1 = btp[(size_t)(jt + 1) * NTOT + r0 + 16 + c];
      const float* en = etb + (jt + 1) * 64;
      ea = ((const float4*)en)[0];
      eb = ((const float4*)en)[1];
      ec = ((const float4*)en)[2];
      ed = ((const float4*)en)[3];
    }

    // ---- MFMA half 0 (bA), then start next body's half-0 loads ----
#pragma unroll
    for (int q = 0; q < 8; ++q) {
      acc[0][q] = __builtin_amdgcn_mfma_f32_16x16x32_bf16(pa0, bA[q], acc[0][q], 0, 0, 0);
      acc[1][q] = __builtin_amdgcn_mfma_f32_16x16x32_bf16(pa1, bA[q], acc[1][q], 0, 0, 0);
    }
    if (jt + 1 < NITER) { LDH(bA, jt + 1, 0) }

    // ---- MFMA half 1 (bB) ----
#pragma unroll
    for (int q = 0; q < 8; ++q) {
      acc[0][8 + q] = __builtin_amdgcn_mfma_f32_16x16x32_bf16(pa0, bB[q], acc[0][8 + q], 0, 0, 0);
      acc[1][8 + q] = __builtin_amdgcn_mfma_f32_16x16x32_bf16(pa1, bB[q], acc[1][8 + q], 0, 0, 0);
    }
  }
  #undef LDH

  // ---- row-sum reduce: quads -> lanes 0-15, then LDS across waves ----
  lp0 += __shfl_xor(lp0, 16, 64); lp0 += __shfl_xor(lp0, 32, 64);
  lp1 += __shfl_xor(lp1, 16, 64); lp1 += __shfl_xor(lp1, 32, 64);
  if (quad == 0) { sh.lred[w][c] = lp0; sh.lred[w][16 + c] = lp1; }
  __syncthreads();

  float linv[2][4];
  if (w == 0) {
#pragma unroll
    for (int rt = 0; rt < 2; ++rt)
#pragma unroll
      for (int reg = 0; reg < 4; ++reg) {
        int lrow = rt * 16 + quad * 4 + reg;
        float s = 0.f;
#pragma unroll
        for (int wi = 0; wi < 8; ++wi) s += sh.lred[wi][lrow];
        linv[rt][reg] = 1.f / s;
      }
  }
  __syncthreads();

  // ---- log-depth acc reduction over 8 waves, per 128-col half ----
#pragma unroll
  for (int hd = 0; hd < 2; ++hd) {
    if (w >= 4) {
#pragma unroll
      for (int rt = 0; rt < 2; ++rt)
#pragma unroll
        for (int i = 0; i < 8; ++i)
#pragma unroll
          for (int reg = 0; reg < 4; ++reg)
            sh.slab[w - 4][(rt * 16 + quad * 4 + reg) * 128 + i * 16 + c] =
                acc[rt][i + 8 * hd][reg];
    }
    __syncthreads();
    if (w < 4) {
#pragma unroll
      for (int rt = 0; rt < 2; ++rt)
#pragma unroll
        for (int i = 0; i < 8; ++i)
#pragma unroll
          for (int reg = 0; reg < 4; ++reg)
            acc[rt][i + 8 * hd][reg] +=
                sh.slab[w][(rt * 16 + quad * 4 + reg) * 128 + i * 16 + c];
    }
    __syncthreads();
    if (w == 2 || w == 3) {
#pragma unroll
      for (int rt = 0; rt < 2; ++rt)
#pragma unroll
        for (int i = 0; i < 8; ++i)
#pragma unroll
          for (int reg = 0; reg < 4; ++reg)
            sh.slab[w - 2][(rt * 16 + quad * 4 + reg) * 128 + i * 16 + c] =
                acc[rt][i + 8 * hd][reg];
    }
    __syncthreads();
    if (w < 2) {
#pragma unroll
      for (int rt = 0; rt < 2; ++rt)
#pragma unroll
        for (int i = 0; i < 8; ++i)
#pragma unroll
          for (int reg = 0; reg < 4; ++reg)
            acc[rt][i + 8 * hd][reg] +=
                sh.slab[w][(rt * 16 + quad * 4 + reg) * 128 + i * 16 + c];
    }
    __syncthreads();
    if (w == 1) {
#pragma unroll
      for (int rt = 0; rt < 2; ++rt)
#pragma unroll
        for (int i = 0; i < 8; ++i)
#pragma unroll
          for (int reg = 0; reg < 4; ++reg)
            sh.slab[0][(rt * 16 + quad * 4 + reg) * 128 + i * 16 + c] =
                acc[rt][i + 8 * hd][reg];
    }
    __syncthreads();
    if (w == 0) {
#pragma unroll
      for (int rt = 0; rt < 2; ++rt)
#pragma unroll
        for (int i = 0; i < 8; ++i)
#pragma unroll
          for (int reg = 0; reg < 4; ++reg) {
            float v = acc[rt][i + 8 * hd][reg] +
                      sh.slab[0][(rt * 16 + quad * 4 + reg) * 128 + i * 16 + c];
            out[(size_t)(r0 + rt * 16 + quad * 4 + reg) * DDIM +
                hd * 128 + i * 16 + c] = v * linv[rt][reg];
          }
    }
    __syncthreads();
  }
}

extern "C" void kernel_launch(void* const* d_in, const int* in_sizes, int n_in,
                              void* d_out, int out_size, void* d_ws, size_t ws_size,
                              hipStream_t stream) {
  const float* h   = (const float*)d_in[0];
  const int*   adj = (const int*)d_in[1];
  const float* a   = (const float*)d_in[2];
  float* out = (float*)d_out;

  float*    s1    = (float*)d_ws;                        // 8192 f32
  float*    s2    = s1 + NTOT;                           // 8192 f32
  float4*   rc    = (float4*)(s2 + NTOT);                // 8192 float4 (16B aligned at 64KB)
  float2*   etab  = (float2*)(rc + NTOT);                // 8192 float2
  unsigned* bitsT = (unsigned*)(etab + NTOT);            // 256*8192 u32 = 8 MB (at 256KB)
  ushort*   hTf   = (ushort*)(bitsT + (size_t)NWORDS * NTOT);  // ~4.21 MB bf16

  gat_scores<<<NTOT / 4, 256, 0, stream>>>(h, a, s1, s2, rc, etab);
  gat_pack<<<dim3(NTOT / 64, 4), 256, 0, stream>>>(adj, bitsT);
  gat_hpack<<<NTOT / 64, 256, 0, stream>>>(h, hTf);
  gat_attn<<<NTOT / ROWS, 512, 0, stream>>>(hTf, bitsT, rc, etab, out);
}